// Round 7
// baseline (233.225 us; speedup 1.0000x reference)
//
#include <hip/hip_runtime.h>
#include <hip/hip_bf16.h>

typedef __bf16 bf16;
typedef __bf16 bf16x8 __attribute__((ext_vector_type(8)));
typedef float f32x4 __attribute__((ext_vector_type(4)));

#define MFMA_16x16x32(A, B, C) __builtin_amdgcn_mfma_f32_16x16x32_bf16(A, B, C, 0, 0, 0)

static_assert(sizeof(bf16x8) == 16, "bf16x8 must be 16B");

__device__ __forceinline__ bf16x8 cast8(float4 lo, float4 hi) {
  return (bf16x8){(bf16)lo.x, (bf16)lo.y, (bf16)lo.z, (bf16)lo.w,
                  (bf16)hi.x, (bf16)hi.y, (bf16)hi.z, (bf16)hi.w};
}

// ---------------------------------------------------------------------------
// Kernel 0: cast + transpose weights: Wt[p][h][c] = W_p[c][h].
// ---------------------------------------------------------------------------
__global__ __launch_bounds__(256) void wtrans_kernel(
    const float* __restrict__ Wq, const float* __restrict__ Wk,
    const float* __restrict__ Wv, bf16* __restrict__ Wt)
{
  int idx = blockIdx.x * 256 + threadIdx.x;   // 3*64*1024
  int p = idx >> 16;
  int rem = idx & 65535;
  int h = rem >> 10;
  int c = rem & 1023;
  const float* W = (p == 0) ? Wq : (p == 1) ? Wk : Wv;
  Wt[idx] = (bf16)W[c * 64 + h];
}

// ---------------------------------------------------------------------------
// Kernel 1: projections — barrier-free free-running streaming GEMM.
//   bid&1==0 : Q = q @ Wq        bid&1==1 : K = k @ Wk, V = k @ Wv
// NO LDS, NO barriers, NO vmcnt(0): every wave streams independently.
// Per wave: 16 rows; per K-step (BK=32): 2 float4 A-loads (HBM/L3) and
// 4 (p=0) / 8 (p=1) bf16x8 B-fragment loads straight from the L2-resident
// transposed weights. BOTH A and B are prefetched one full K-step ahead in
// ping-pong named register sets (static indexing) — the compiler places a
// counted s_waitcnt vmcnt(N) at each consume point, so loads stay in
// flight continuously. This fixes R1's per-step L2-latency chain (B loaded
// at use) while keeping R1's 7 TB/s-proven barrier-free delivery path.
// Grid 1024 blocks = 4 blocks/CU; ~130 VGPR -> 12-16 waves/CU.
// ---------------------------------------------------------------------------
__global__ __launch_bounds__(256) void proj_kernel(
    const float* __restrict__ qin, const float* __restrict__ kin,
    const bf16* __restrict__ Wt,
    bf16* __restrict__ Qb, bf16* __restrict__ Kb, bf16* __restrict__ Vtb)
{
  const int bid = blockIdx.x;            // 0..1023
  const int p = bid & 1;                 // 0: Q   1: K+V
  const int m0 = (bid >> 1) * 64;
  const float* A = p ? kin : qin;

  const int tid = threadIdx.x;
  const int lane = tid & 63;
  const int w = tid >> 6;
  const int g = lane >> 4;
  const int r = lane & 15;

  // A fragment pointer: lane (g,r) covers row m0+w*16+r, k-slice g*8..g*8+7
  const float* ap = A + (size_t)(m0 + w * 16 + r) * 1024 + g * 8;
  // B fragment pointers: W-row (= output col) cf*16+r, same k-slice
  const bf16* bq = Wt + (size_t)(p ? 1 : 0) * 65536 + (size_t)r * 1024 + g * 8;
  const bf16* bv = Wt + (size_t)2 * 65536 + (size_t)r * 1024 + g * 8;

  f32x4 acc0[4], acc1[4];
  #pragma unroll
  for (int cf = 0; cf < 4; cf++) {
    acc0[cf] = (f32x4){0.f, 0.f, 0.f, 0.f};
    acc1[cf] = (f32x4){0.f, 0.f, 0.f, 0.f};
  }

  // ping-pong named prefetch sets (static indexing — rule #20)
  float4 Aa0, Ab0, Aa1, Ab1;
  bf16x8 Bq0[4], Bq1[4], Bv0[4], Bv1[4];

#define ISS(S, K0)                                                        \
  do {                                                                    \
    Aa##S = *(const float4*)(ap + (K0));                                  \
    Ab##S = *(const float4*)(ap + (K0) + 4);                              \
    _Pragma("unroll")                                                     \
    for (int cf = 0; cf < 4; cf++)                                        \
      Bq##S[cf] = *(const bf16x8*)(bq + cf * 16384 + (K0));               \
    if (p) {                                                              \
      _Pragma("unroll")                                                   \
      for (int cf = 0; cf < 4; cf++)                                      \
        Bv##S[cf] = *(const bf16x8*)(bv + cf * 16384 + (K0));             \
    }                                                                     \
  } while (0)

#define STEP(S)                                                           \
  do {                                                                    \
    bf16x8 af = cast8(Aa##S, Ab##S);                                      \
    _Pragma("unroll")                                                     \
    for (int cf = 0; cf < 4; cf++)                                        \
      acc0[cf] = MFMA_16x16x32(af, Bq##S[cf], acc0[cf]);                  \
    if (p) {                                                              \
      _Pragma("unroll")                                                   \
      for (int cf = 0; cf < 4; cf++)                                      \
        acc1[cf] = MFMA_16x16x32(af, Bv##S[cf], acc1[cf]);                \
    }                                                                     \
  } while (0)

  // prologue: 2 K-steps in flight
  ISS(0, 0);
  ISS(1, 32);

  #pragma unroll 1
  for (int j = 0; j < 15; ++j) {
    STEP(0);                       // consume k-step 2j (vmcnt counted here)
    ISS(0, (2 * j + 2) * 32);      // refill set0 <- 2j+2
    STEP(1);                       // consume 2j+1
    ISS(1, (2 * j + 3) * 32);      // refill set1 <- 2j+3
  }
  STEP(0);   // k-step 30
  STEP(1);   // k-step 31

#undef ISS
#undef STEP

  // --- epilogue: C/D layout row=(l>>4)*4+j, col=l&15 ---
  #pragma unroll
  for (int cf = 0; cf < 4; cf++) {
    #pragma unroll
    for (int jj = 0; jj < 4; jj++) {
      int rg = m0 + w * 16 + g * 4 + jj;
      int col = cf * 16 + r;
      if (p == 0) {
        Qb[(size_t)rg * 64 + col] = (bf16)acc0[cf][jj];
      } else {
        Kb[(size_t)rg * 64 + col] = (bf16)acc0[cf][jj];
        int bb = rg >> 11, t2 = rg & 2047;
        Vtb[(size_t)(bb * 64 + col) * 2048 + t2] = (bf16)acc1[cf][jj];
      }
    }
  }
}

// ---------------------------------------------------------------------------
// Kernel 2: causal flash attention (unchanged).
// ---------------------------------------------------------------------------
__global__ __launch_bounds__(256) void attn_kernel(
    const bf16* __restrict__ Qb, const bf16* __restrict__ Kb,
    const bf16* __restrict__ Vtb, float* __restrict__ out)
{
  const int qt = (int)(gridDim.x - 1 - blockIdx.x);   // heavy blocks first
  const int b = blockIdx.y;
  const int tid = threadIdx.x;
  const int lane = tid & 63;
  const int w = tid >> 6;
  const int g = lane >> 4;
  const int r = lane & 15;

  __shared__ __align__(16) bf16 Ks[64][80];
  __shared__ __align__(16) bf16 Vs[64][80];
  __shared__ __align__(16) bf16 Ps[4][16][80];

  const int q0 = qt * 64 + w * 16;
  const bf16* qp = Qb + (size_t)(b * 2048 + q0 + r) * 64 + g * 8;
  const bf16x8 qf0 = *(const bf16x8*)qp;
  const bf16x8 qf1 = *(const bf16x8*)(qp + 32);

  f32x4 acc_o[4];
  #pragma unroll
  for (int hf = 0; hf < 4; hf++) acc_o[hf] = (f32x4){0.f, 0.f, 0.f, 0.f};
  float m_r[4] = {-1e30f, -1e30f, -1e30f, -1e30f};
  float l_r[4] = {0.f, 0.f, 0.f, 0.f};
  const float scale = 0.03125f;   // 1/sqrt(1024)

  const int sh = tid >> 2;
  const int sc = (tid & 3) * 16;

  for (int kv = 0; kv <= qt; kv++) {
    {
      const bf16* kp = Kb + (size_t)(b * 2048 + kv * 64 + sh) * 64 + sc;
      *(bf16x8*)&Ks[sh][sc]     = *(const bf16x8*)kp;
      *(bf16x8*)&Ks[sh][sc + 8] = *(const bf16x8*)(kp + 8);
      const bf16* vp = Vtb + (size_t)(b * 64 + sh) * 2048 + kv * 64 + sc;
      *(bf16x8*)&Vs[sh][sc]     = *(const bf16x8*)vp;
      *(bf16x8*)&Vs[sh][sc + 8] = *(const bf16x8*)(vp + 8);
    }
    __syncthreads();

    f32x4 s[4];
    #pragma unroll
    for (int cf = 0; cf < 4; cf++) {
      bf16x8 kf0 = *(const bf16x8*)&Ks[cf * 16 + r][g * 8];
      bf16x8 kf1 = *(const bf16x8*)&Ks[cf * 16 + r][32 + g * 8];
      f32x4 t = (f32x4){0.f, 0.f, 0.f, 0.f};
      t = MFMA_16x16x32(qf0, kf0, t);
      t = MFMA_16x16x32(qf1, kf1, t);
      s[cf] = t;
    }

    const bool diag = (kv == qt);
    float pm[4] = {-1e30f, -1e30f, -1e30f, -1e30f};
    #pragma unroll
    for (int cf = 0; cf < 4; cf++) {
      #pragma unroll
      for (int j = 0; j < 4; j++) {
        float v = s[cf][j] * scale;
        if (diag && (cf * 16 + r) > (w * 16 + g * 4 + j)) v = -1e30f;
        s[cf][j] = v;
        pm[j] = fmaxf(pm[j], v);
      }
    }
    #pragma unroll
    for (int j = 0; j < 4; j++) {
      #pragma unroll
      for (int msk = 1; msk < 16; msk <<= 1)
        pm[j] = fmaxf(pm[j], __shfl_xor(pm[j], msk, 64));
    }
    float corr[4];
    #pragma unroll
    for (int j = 0; j < 4; j++) {
      float mn = fmaxf(m_r[j], pm[j]);
      corr[j] = __expf(m_r[j] - mn);
      m_r[j] = mn;
    }
    float rs[4] = {0.f, 0.f, 0.f, 0.f};
    #pragma unroll
    for (int cf = 0; cf < 4; cf++) {
      #pragma unroll
      for (int j = 0; j < 4; j++) {
        float pv = __expf(s[cf][j] - m_r[j]);
        s[cf][j] = pv;
        rs[j] += pv;
      }
    }
    #pragma unroll
    for (int j = 0; j < 4; j++) {
      #pragma unroll
      for (int msk = 1; msk < 16; msk <<= 1)
        rs[j] += __shfl_xor(rs[j], msk, 64);
      l_r[j] = l_r[j] * corr[j] + rs[j];
    }
    #pragma unroll
    for (int hf = 0; hf < 4; hf++)
      #pragma unroll
      for (int j = 0; j < 4; j++)
        acc_o[hf][j] *= corr[j];

    #pragma unroll
    for (int cf = 0; cf < 4; cf++)
      #pragma unroll
      for (int j = 0; j < 4; j++)
        Ps[w][g * 4 + j][cf * 16 + r] = (bf16)s[cf][j];

    __syncthreads();

    #pragma unroll
    for (int ss = 0; ss < 2; ss++) {
      bf16x8 pf = *(const bf16x8*)&Ps[w][r][ss * 32 + g * 8];
      #pragma unroll
      for (int hf = 0; hf < 4; hf++) {
        bf16x8 vf = *(const bf16x8*)&Vs[hf * 16 + r][ss * 32 + g * 8];
        acc_o[hf] = MFMA_16x16x32(pf, vf, acc_o[hf]);
      }
    }
    __syncthreads();
  }

  float inv[4];
  #pragma unroll
  for (int j = 0; j < 4; j++) inv[j] = 1.0f / l_r[j];
  const size_t ob = (size_t)(b * 2048 + q0) * 64;
  #pragma unroll
  for (int hf = 0; hf < 4; hf++)
    #pragma unroll
    for (int j = 0; j < 4; j++)
      out[ob + (size_t)(g * 4 + j) * 64 + hf * 16 + r] = acc_o[hf][j] * inv[j];
}

// ---------------------------------------------------------------------------
extern "C" void kernel_launch(void* const* d_in, const int* in_sizes, int n_in,
                              void* d_out, int out_size, void* d_ws, size_t ws_size,
                              hipStream_t stream)
{
  const float* q  = (const float*)d_in[0];
  const float* k  = (const float*)d_in[1];
  const float* Wq = (const float*)d_in[2];
  const float* Wk = (const float*)d_in[3];
  const float* Wv = (const float*)d_in[4];
  float* out = (float*)d_out;

  char* ws = (char*)d_ws;
  bf16* Qb  = (bf16*)(ws);                      // [16*2048][64] bf16, 4MB
  bf16* Kb  = (bf16*)(ws + (4u << 20));         // [16*2048][64] bf16, 4MB
  bf16* Vtb = (bf16*)(ws + (8u << 20));         // [16][64][2048] bf16, 4MB
  bf16* Wt  = (bf16*)(ws + (12u << 20));        // [3][64][1024] bf16, 384KB

  hipLaunchKernelGGL(wtrans_kernel, dim3(768), dim3(256), 0, stream,
                     Wq, Wk, Wv, Wt);
  hipLaunchKernelGGL(proj_kernel, dim3(1024), dim3(256), 0, stream,
                     q, k, Wt, Qb, Kb, Vtb);
  hipLaunchKernelGGL(attn_kernel, dim3(32, 16), dim3(256), 0, stream,
                     Qb, Kb, Vtb, out);
}

// Round 8
// 135.523 us; speedup vs baseline: 1.7209x; 1.7209x over previous
//
#include <hip/hip_runtime.h>
#include <hip/hip_bf16.h>

typedef __bf16 bf16;
typedef __bf16 bf16x8 __attribute__((ext_vector_type(8)));
typedef float f32x4 __attribute__((ext_vector_type(4)));

#define MFMA_16x16x32(A, B, C) __builtin_amdgcn_mfma_f32_16x16x32_bf16(A, B, C, 0, 0, 0)

static_assert(sizeof(bf16x8) == 16, "bf16x8 must be 16B");

__device__ __forceinline__ bf16x8 cast8(float4 lo, float4 hi) {
  return (bf16x8){(bf16)lo.x, (bf16)lo.y, (bf16)lo.z, (bf16)lo.w,
                  (bf16)hi.x, (bf16)hi.y, (bf16)hi.z, (bf16)hi.w};
}

// ---------------------------------------------------------------------------
// Kernel 0: cast + transpose weights: Wt[p][h][c] = W_p[c][h].
// ---------------------------------------------------------------------------
__global__ __launch_bounds__(256) void wtrans_kernel(
    const float* __restrict__ Wq, const float* __restrict__ Wk,
    const float* __restrict__ Wv, bf16* __restrict__ Wt)
{
  int idx = blockIdx.x * 256 + threadIdx.x;   // 3*64*1024
  int p = idx >> 16;
  int rem = idx & 65535;
  int h = rem >> 10;
  int c = rem & 1023;
  const float* W = (p == 0) ? Wq : (p == 1) ? Wk : Wv;
  Wt[idx] = (bf16)W[c * 64 + h];
}

// ---------------------------------------------------------------------------
// Kernel 1: projections — traffic-minimal, drain-free hybrid.
//   bid&1==0 : Q = q @ Wq        bid&1==1 : K = k @ Wk, V = k @ Wv
// Unified-model design: the binding resource is ~6.3 TB/s of VMEM delivery
// (1KB per wave-instruction). So: (a) A (the mandatory 256 MB) uses R1's
// per-lane fragment loads — every instruction delivers 1KB of useful data —
// with a 2-substep ping-pong register prefetch (only 32 VGPR, so regalloc
// keeps it, unlike R6's 112); (b) B goes through LDS ONCE per BK=64 step
// (98 MB total vs R1's 660 MB of L2 re-reads); (c) sync is ONE raw
// s_barrier + lgkmcnt(0) per BK-step (16 total) — no __syncthreads
// vmcnt(0) drain (R4/R5's killer), no global_load_lds DMA (R2/R3's).
// BM=128 (4 waves x 32 rows, rf=2), grid 512 = 2 blocks/CU, LDS 36 KB.
// ---------------------------------------------------------------------------
__global__ __launch_bounds__(256) void proj_kernel(
    const float* __restrict__ qin, const float* __restrict__ kin,
    const bf16* __restrict__ Wt,
    bf16* __restrict__ Qb, bf16* __restrict__ Kb, bf16* __restrict__ Vtb)
{
  const int bid = blockIdx.x;            // 0..511
  const int p = bid & 1;                 // 0: Q   1: K+V
  const int m0 = (bid >> 1) * 128;
  const float* A = p ? kin : qin;

  __shared__ __align__(16) bf16 Bs[2][2][64][72];   // [buf][mat][row][64+8pad]

  const int tid = threadIdx.x;
  const int lane = tid & 63;
  const int w = tid >> 6;
  const int g = lane >> 4;
  const int r = lane & 15;

  // B staging: thread -> (row srow, 16-col slice scol) of the 64x64 tile
  const int srow = tid >> 2;
  const int scol = (tid & 3) * 16;
  const bf16* bsrc0 = Wt + (size_t)(p ? 1 : 0) * 65536 + (size_t)srow * 1024 + scol;
  const bf16* bsrc1 = Wt + (size_t)2 * 65536 + (size_t)srow * 1024 + scol;

  // A fragment pointers: lane (g,r), rf in {0,1}: row m0+w*32+rf*16+r
  const float* ap0 = A + (size_t)(m0 + w * 32 + r) * 1024 + g * 8;
  const float* ap1 = ap0 + 16 * 1024;

  f32x4 acc[2][2][4];   // [mat][rf][cf]
  #pragma unroll
  for (int mt = 0; mt < 2; mt++)
    #pragma unroll
    for (int rf = 0; rf < 2; rf++)
      #pragma unroll
      for (int cf = 0; cf < 4; cf++)
        acc[mt][rf][cf] = (f32x4){0.f, 0.f, 0.f, 0.f};

  // A ping-pong prefetch sets (static indices only)
  float4 Aa0[2], Ab0[2], Aa1[2], Ab1[2];
  // B staging registers
  bf16x8 Br[2][2];

#define ISSB(K0)                                                          \
  do {                                                                    \
    Br[0][0] = *(const bf16x8*)(bsrc0 + (K0));                            \
    Br[0][1] = *(const bf16x8*)(bsrc0 + (K0) + 8);                        \
    if (p) {                                                              \
      Br[1][0] = *(const bf16x8*)(bsrc1 + (K0));                          \
      Br[1][1] = *(const bf16x8*)(bsrc1 + (K0) + 8);                      \
    }                                                                     \
  } while (0)

#define WRB(BUF)                                                          \
  do {                                                                    \
    *(bf16x8*)&Bs[BUF][0][srow][scol]     = Br[0][0];                     \
    *(bf16x8*)&Bs[BUF][0][srow][scol + 8] = Br[0][1];                     \
    if (p) {                                                              \
      *(bf16x8*)&Bs[BUF][1][srow][scol]     = Br[1][0];                   \
      *(bf16x8*)&Bs[BUF][1][srow][scol + 8] = Br[1][1];                   \
    }                                                                     \
  } while (0)

#define ISSA(S, U)                                                        \
  do {                                                                    \
    Aa##S[0] = *(const float4*)(ap0 + (U) * 32);                          \
    Ab##S[0] = *(const float4*)(ap0 + (U) * 32 + 4);                      \
    Aa##S[1] = *(const float4*)(ap1 + (U) * 32);                          \
    Ab##S[1] = *(const float4*)(ap1 + (U) * 32 + 4);                      \
  } while (0)

#define STEPA(S, CUR, SS)                                                 \
  do {                                                                    \
    bf16x8 af0 = cast8(Aa##S[0], Ab##S[0]);                               \
    bf16x8 af1 = cast8(Aa##S[1], Ab##S[1]);                               \
    _Pragma("unroll")                                                     \
    for (int cf = 0; cf < 4; cf++) {                                      \
      bf16x8 b0 = *(const bf16x8*)&Bs[CUR][0][cf * 16 + r][(SS) * 32 + g * 8]; \
      acc[0][0][cf] = MFMA_16x16x32(af0, b0, acc[0][0][cf]);              \
      acc[0][1][cf] = MFMA_16x16x32(af1, b0, acc[0][1][cf]);              \
    }                                                                     \
    if (p) {                                                              \
      _Pragma("unroll")                                                   \
      for (int cf = 0; cf < 4; cf++) {                                    \
        bf16x8 b1 = *(const bf16x8*)&Bs[CUR][1][cf * 16 + r][(SS) * 32 + g * 8]; \
        acc[1][0][cf] = MFMA_16x16x32(af0, b1, acc[1][0][cf]);            \
        acc[1][1][cf] = MFMA_16x16x32(af1, b1, acc[1][1][cf]);            \
      }                                                                   \
    }                                                                     \
  } while (0)

#define LGKM_BARRIER() \
  asm volatile("s_waitcnt lgkmcnt(0)\n\ts_barrier" ::: "memory")

  // --- prologue ---
  ISSB(0);                 // B(0) -> regs
  ISSA(0, 0);              // A substep 0
  ISSA(1, 1);              // A substep 1
  WRB(0);                  // counted vmcnt waits only B(0); A stays in flight
  ISSB(64);                // B(1) -> regs (in flight across step 0)
  LGKM_BARRIER();

  // steady state: LDS[t&1] = B(t); Br holds B(t+1) in flight
  #pragma unroll 1
  for (int t = 0; t < 15; ++t) {
    const int cur = t & 1;
    STEPA(0, cur, 0);            // consume A(2t)   [vmcnt counted, != 0]
    ISSA(0, 2 * t + 2);          // refill set0
    STEPA(1, cur, 1);            // consume A(2t+1)
    ISSA(1, 2 * t + 3);          // refill set1
    WRB(cur ^ 1);                // stage B(t+1)  [waits its 2-4 loads only]
    if (t < 14) ISSB((t + 2) * 64);
    LGKM_BARRIER();              // writes visible; NO vmcnt drain
  }
  // t = 15 (cur = 1): last tile, no staging
  STEPA(0, 1, 0);
  STEPA(1, 1, 1);

#undef ISSB
#undef WRB
#undef ISSA
#undef STEPA
#undef LGKM_BARRIER

  // --- epilogue: C/D layout row=(l>>4)*4+j, col=l&15 ---
  #pragma unroll
  for (int rf = 0; rf < 2; rf++) {
    #pragma unroll
    for (int cf = 0; cf < 4; cf++) {
      #pragma unroll
      for (int jj = 0; jj < 4; jj++) {
        int rg = m0 + w * 32 + rf * 16 + g * 4 + jj;
        int col = cf * 16 + r;
        if (p == 0) {
          Qb[(size_t)rg * 64 + col] = (bf16)acc[0][rf][cf][jj];
        } else {
          Kb[(size_t)rg * 64 + col] = (bf16)acc[0][rf][cf][jj];
          int bb = rg >> 11, t2 = rg & 2047;
          Vtb[(size_t)(bb * 64 + col) * 2048 + t2] = (bf16)acc[1][rf][cf][jj];
        }
      }
    }
  }
}

// ---------------------------------------------------------------------------
// Kernel 2: causal flash attention (unchanged).
// ---------------------------------------------------------------------------
__global__ __launch_bounds__(256) void attn_kernel(
    const bf16* __restrict__ Qb, const bf16* __restrict__ Kb,
    const bf16* __restrict__ Vtb, float* __restrict__ out)
{
  const int qt = (int)(gridDim.x - 1 - blockIdx.x);   // heavy blocks first
  const int b = blockIdx.y;
  const int tid = threadIdx.x;
  const int lane = tid & 63;
  const int w = tid >> 6;
  const int g = lane >> 4;
  const int r = lane & 15;

  __shared__ __align__(16) bf16 Ks[64][80];
  __shared__ __align__(16) bf16 Vs[64][80];
  __shared__ __align__(16) bf16 Ps[4][16][80];

  const int q0 = qt * 64 + w * 16;
  const bf16* qp = Qb + (size_t)(b * 2048 + q0 + r) * 64 + g * 8;
  const bf16x8 qf0 = *(const bf16x8*)qp;
  const bf16x8 qf1 = *(const bf16x8*)(qp + 32);

  f32x4 acc_o[4];
  #pragma unroll
  for (int hf = 0; hf < 4; hf++) acc_o[hf] = (f32x4){0.f, 0.f, 0.f, 0.f};
  float m_r[4] = {-1e30f, -1e30f, -1e30f, -1e30f};
  float l_r[4] = {0.f, 0.f, 0.f, 0.f};
  const float scale = 0.03125f;   // 1/sqrt(1024)

  const int sh = tid >> 2;
  const int sc = (tid & 3) * 16;

  for (int kv = 0; kv <= qt; kv++) {
    {
      const bf16* kp = Kb + (size_t)(b * 2048 + kv * 64 + sh) * 64 + sc;
      *(bf16x8*)&Ks[sh][sc]     = *(const bf16x8*)kp;
      *(bf16x8*)&Ks[sh][sc + 8] = *(const bf16x8*)(kp + 8);
      const bf16* vp = Vtb + (size_t)(b * 64 + sh) * 2048 + kv * 64 + sc;
      *(bf16x8*)&Vs[sh][sc]     = *(const bf16x8*)vp;
      *(bf16x8*)&Vs[sh][sc + 8] = *(const bf16x8*)(vp + 8);
    }
    __syncthreads();

    f32x4 s[4];
    #pragma unroll
    for (int cf = 0; cf < 4; cf++) {
      bf16x8 kf0 = *(const bf16x8*)&Ks[cf * 16 + r][g * 8];
      bf16x8 kf1 = *(const bf16x8*)&Ks[cf * 16 + r][32 + g * 8];
      f32x4 t = (f32x4){0.f, 0.f, 0.f, 0.f};
      t = MFMA_16x16x32(qf0, kf0, t);
      t = MFMA_16x16x32(qf1, kf1, t);
      s[cf] = t;
    }

    const bool diag = (kv == qt);
    float pm[4] = {-1e30f, -1e30f, -1e30f, -1e30f};
    #pragma unroll
    for (int cf = 0; cf < 4; cf++) {
      #pragma unroll
      for (int j = 0; j < 4; j++) {
        float v = s[cf][j] * scale;
        if (diag && (cf * 16 + r) > (w * 16 + g * 4 + j)) v = -1e30f;
        s[cf][j] = v;
        pm[j] = fmaxf(pm[j], v);
      }
    }
    #pragma unroll
    for (int j = 0; j < 4; j++) {
      #pragma unroll
      for (int msk = 1; msk < 16; msk <<= 1)
        pm[j] = fmaxf(pm[j], __shfl_xor(pm[j], msk, 64));
    }
    float corr[4];
    #pragma unroll
    for (int j = 0; j < 4; j++) {
      float mn = fmaxf(m_r[j], pm[j]);
      corr[j] = __expf(m_r[j] - mn);
      m_r[j] = mn;
    }
    float rs[4] = {0.f, 0.f, 0.f, 0.f};
    #pragma unroll
    for (int cf = 0; cf < 4; cf++) {
      #pragma unroll
      for (int j = 0; j < 4; j++) {
        float pv = __expf(s[cf][j] - m_r[j]);
        s[cf][j] = pv;
        rs[j] += pv;
      }
    }
    #pragma unroll
    for (int j = 0; j < 4; j++) {
      #pragma unroll
      for (int msk = 1; msk < 16; msk <<= 1)
        rs[j] += __shfl_xor(rs[j], msk, 64);
      l_r[j] = l_r[j] * corr[j] + rs[j];
    }
    #pragma unroll
    for (int hf = 0; hf < 4; hf++)
      #pragma unroll
      for (int j = 0; j < 4; j++)
        acc_o[hf][j] *= corr[j];

    #pragma unroll
    for (int cf = 0; cf < 4; cf++)
      #pragma unroll
      for (int j = 0; j < 4; j++)
        Ps[w][g * 4 + j][cf * 16 + r] = (bf16)s[cf][j];

    __syncthreads();

    #pragma unroll
    for (int ss = 0; ss < 2; ss++) {
      bf16x8 pf = *(const bf16x8*)&Ps[w][r][ss * 32 + g * 8];
      #pragma unroll
      for (int hf = 0; hf < 4; hf++) {
        bf16x8 vf = *(const bf16x8*)&Vs[hf * 16 + r][ss * 32 + g * 8];
        acc_o[hf] = MFMA_16x16x32(pf, vf, acc_o[hf]);
      }
    }
    __syncthreads();
  }

  float inv[4];
  #pragma unroll
  for (int j = 0; j < 4; j++) inv[j] = 1.0f / l_r[j];
  const size_t ob = (size_t)(b * 2048 + q0) * 64;
  #pragma unroll
  for (int hf = 0; hf < 4; hf++)
    #pragma unroll
    for (int j = 0; j < 4; j++)
      out[ob + (size_t)(g * 4 + j) * 64 + hf * 16 + r] = acc_o[hf][j] * inv[j];
}

// ---------------------------------------------------------------------------
extern "C" void kernel_launch(void* const* d_in, const int* in_sizes, int n_in,
                              void* d_out, int out_size, void* d_ws, size_t ws_size,
                              hipStream_t stream)
{
  const float* q  = (const float*)d_in[0];
  const float* k  = (const float*)d_in[1];
  const float* Wq = (const float*)d_in[2];
  const float* Wk = (const float*)d_in[3];
  const float* Wv = (const float*)d_in[4];
  float* out = (float*)d_out;

  char* ws = (char*)d_ws;
  bf16* Qb  = (bf16*)(ws);                      // [16*2048][64] bf16, 4MB
  bf16* Kb  = (bf16*)(ws + (4u << 20));         // [16*2048][64] bf16, 4MB
  bf16* Vtb = (bf16*)(ws + (8u << 20));         // [16][64][2048] bf16, 4MB
  bf16* Wt  = (bf16*)(ws + (12u << 20));        // [3][64][1024] bf16, 384KB

  hipLaunchKernelGGL(wtrans_kernel, dim3(768), dim3(256), 0, stream,
                     Wq, Wk, Wv, Wt);
  hipLaunchKernelGGL(proj_kernel, dim3(512), dim3(256), 0, stream,
                     q, k, Wt, Qb, Kb, Vtb);
  hipLaunchKernelGGL(attn_kernel, dim3(32, 16), dim3(256), 0, stream,
                     Qb, Kb, Vtb, out);
}